// Round 3
// baseline (1720.145 us; speedup 1.0000x reference)
//
#include <hip/hip_runtime.h>
#include <stdint.h>

typedef unsigned short u16;
typedef __bf16 bf16x8 __attribute__((ext_vector_type(8)));
typedef float f32x4 __attribute__((ext_vector_type(4)));

__device__ __forceinline__ float b2f(u16 u) {
    union { float f; uint32_t i; } x; x.i = ((uint32_t)u) << 16; return x.f;
}
__device__ __forceinline__ u16 f2b(float f) {
    union { float f; uint32_t i; } x; x.f = f;
    uint32_t r = (x.i + 0x7fffu + ((x.i >> 16) & 1u)) >> 16;
    return (u16)r;
}

// ---------------- CPB: tab = relu(rel @ W1^T + b1) @ W2^T ----------------
__global__ __launch_bounds__(512)
void cpb_tab_kernel(const float* __restrict__ w1, const float* __restrict__ b1,
                    const float* __restrict__ w2, float* __restrict__ tab) {
    __shared__ float hbuf[512];
    int p = blockIdx.x, j = threadIdx.x;
    int i0 = p / 13, i1 = p % 13;
    float c0 = (i0 - 6) * (8.0f / 6.0f), c1 = (i1 - 6) * (8.0f / 6.0f);
    float r0 = copysignf(log2f(fabsf(c0) + 1.0f) * (1.0f / 3.0f), c0);
    float r1 = copysignf(log2f(fabsf(c1) + 1.0f) * (1.0f / 3.0f), c1);
    float h = r0 * w1[j * 2] + r1 * w1[j * 2 + 1] + b1[j];
    hbuf[j] = fmaxf(h, 0.0f);
    __syncthreads();
    if (j < 12) {
        float s = 0.0f;
        for (int t = 0; t < 512; t++) s += w2[j * 512 + t] * hbuf[t];
        tab[p * 12 + j] = s;
    }
}

__global__ __launch_bounds__(256)
void cpb_gather_kernel(const float* __restrict__ tab, float* __restrict__ rpb) {
    int idx = blockIdx.x * 256 + threadIdx.x;
    if (idx >= 12 * 2401) return;
    int h = idx / 2401, r = idx % 2401, i = r / 49, j = r % 49;
    int d = (i / 7 - j / 7 + 6) * 13 + (i % 7 - j % 7 + 6);
    float v = tab[d * 12 + h];
    rpb[idx] = 16.0f / (1.0f + expf(-v));
}

// ---------------- LN stats: one wave per token (raster order, fp32 in) ----------------
__global__ __launch_bounds__(256)
void ln_stats_kernel(const float* __restrict__ in, float2* __restrict__ st) {
    int wave = threadIdx.x >> 6, lane = threadIdx.x & 63;
    int tok = blockIdx.x * 4 + wave;
    size_t src = (size_t)tok * 384;
    float s = 0.0f, s2 = 0.0f;
#pragma unroll
    for (int i = 0; i < 6; i++) {
        float t = in[src + i * 64 + lane];
        s += t; s2 += t * t;
    }
#pragma unroll
    for (int m = 32; m >= 1; m >>= 1) { s += __shfl_xor(s, m, 64); s2 += __shfl_xor(s2, m, 64); }
    if (lane == 0) {
        float mu = s * (1.0f / 384.0f);
        float var = s2 * (1.0f / 384.0f) - mu * mu;
        st[tok] = make_float2(mu, rsqrtf(var + 1e-5f));
    }
}

// ---------------- MFMA GEMM: fp32/bf16 A sources, fp32 W, fused epilogues ----------------
enum { SRC_WINLN = 0, SRC_HEADMAJ = 1, SRC_RASTLN = 2, SRC_PLAIN = 3 };
enum { EPI_QKV = 0, EPI_PROJ = 1, EPI_MLP1 = 2, EPI_MLP2 = 3 };
#define LDP 40

template <int SRC, int EPI>
__global__ __launch_bounds__(256)
void gemm_mfma(const void* __restrict__ Av, const float* __restrict__ W,
               const float* __restrict__ bias, int K,
               const float2* __restrict__ stats,
               const float* __restrict__ lng, const float* __restrict__ lnb,
               u16* __restrict__ o0, u16* __restrict__ o1, u16* __restrict__ o2,
               const float* __restrict__ xres, float* __restrict__ dout) {
    const float* Af = (const float*)Av;
    const u16*   Ab = (const u16*)Av;
    const int tid = threadIdx.x;
    const int wave = tid >> 6, lane = tid & 63, quad = lane >> 4, l16 = lane & 15;
    const int wm = (wave >> 1) * 64, wn = (wave & 1) * 64;
    const int m0 = blockIdx.y * 128, n0 = blockIdx.x * 128;
    __shared__ alignas(16) u16 lA[128 * LDP];
    __shared__ alignas(16) u16 lB[128 * LDP];
    f32x4 acc[4][4] = {};

    // fixed per-thread staging rows: precompute source base + LN stats
    size_t abase[2];
    float amu[2] = {0.f, 0.f}, arst[2] = {0.f, 0.f};
#pragma unroll
    for (int s = 0; s < 2; s++) {
        int row = (tid + s * 256) >> 2;
        int grow = m0 + row;
        if (SRC == SRC_WINLN) {
            int widx = grow / 49, n = grow % 49;
            int bb = widx >> 6, wi = widx & 63;
            int hs = (wi >> 3) * 7 + n / 7, wsr = (wi & 7) * 7 + n % 7;
            int h = hs + 3; if (h >= 56) h -= 56;
            int w = wsr + 3; if (w >= 56) w -= 56;
            int tok = bb * 3136 + h * 56 + w;
            abase[s] = (size_t)tok * 384;
            float2 st = stats[tok]; amu[s] = st.x; arst[s] = st.y;
        } else if (SRC == SRC_HEADMAJ) {
            int widx = grow / 49, n = grow % 49;
            abase[s] = (size_t)widx * 18816 + (size_t)n * 32;   // 12*1568
        } else if (SRC == SRC_RASTLN) {
            abase[s] = (size_t)grow * 384;
            float2 st = stats[grow]; amu[s] = st.x; arst[s] = st.y;
        } else {
            abase[s] = (size_t)grow * (size_t)K;
        }
    }

    for (int kk = 0; kk < K; kk += 32) {
        __syncthreads();
#pragma unroll
        for (int s = 0; s < 2; s++) {
            int c = tid + s * 256;
            int row = c >> 2, seg = c & 3;
            // ---- A ----
            u16 oa[8];
            if (SRC == SRC_HEADMAJ || SRC == SRC_PLAIN) {
                size_t off = (SRC == SRC_HEADMAJ)
                                 ? (size_t)(kk >> 5) * 1568 + seg * 8
                                 : (size_t)kk + seg * 8;
                *(int4*)oa = *(const int4*)&Ab[abase[s] + off];
            } else {
                const float* sp = Af + abase[s] + kk + seg * 8;
                float4 r0 = *(const float4*)sp, r1 = *(const float4*)(sp + 4);
                float vv[8] = {r0.x, r0.y, r0.z, r0.w, r1.x, r1.y, r1.z, r1.w};
                int cb = kk + seg * 8;
#pragma unroll
                for (int e = 0; e < 8; e++)
                    oa[e] = f2b((vv[e] - amu[s]) * arst[s] * lng[cb + e] + lnb[cb + e]);
            }
            *(int4*)&lA[row * LDP + seg * 8] = *(int4*)oa;
            // ---- B (fp32 weights -> bf16) ----
            const float* wp = W + (size_t)(n0 + row) * K + kk + seg * 8;
            float4 w0 = *(const float4*)wp, w1 = *(const float4*)(wp + 4);
            float wv[8] = {w0.x, w0.y, w0.z, w0.w, w1.x, w1.y, w1.z, w1.w};
            u16 ob[8];
#pragma unroll
            for (int e = 0; e < 8; e++) ob[e] = f2b(wv[e]);
            *(int4*)&lB[row * LDP + seg * 8] = *(int4*)ob;
        }
        __syncthreads();
        bf16x8 af[4], bfr[4];
#pragma unroll
        for (int t = 0; t < 4; t++)
            af[t] = *(const bf16x8*)&lA[(wm + t * 16 + l16) * LDP + quad * 8];
#pragma unroll
        for (int t = 0; t < 4; t++)
            bfr[t] = *(const bf16x8*)&lB[(wn + t * 16 + l16) * LDP + quad * 8];
#pragma unroll
        for (int i = 0; i < 4; i++)
#pragma unroll
            for (int j = 0; j < 4; j++)
                acc[i][j] = __builtin_amdgcn_mfma_f32_16x16x32_bf16(af[i], bfr[j], acc[i][j], 0, 0, 0);
    }

#pragma unroll
    for (int i = 0; i < 4; i++) {
#pragma unroll
        for (int r = 0; r < 4; r++) {
            int row = m0 + wm + i * 16 + quad * 4 + r;  // token index
            int widx = 0, n = 0;
            size_t pbase = 0;
            if (EPI == EPI_QKV || EPI == EPI_PROJ) { widx = row / 49; n = row % 49; }
            if (EPI == EPI_PROJ) {
                int bb = widx >> 6, wi = widx & 63;
                int hs = (wi >> 3) * 7 + n / 7, wsr = (wi & 7) * 7 + n % 7;
                int h = hs + 3; if (h >= 56) h -= 56;
                int w = wsr + 3; if (w >= 56) w -= 56;
                pbase = (((size_t)bb * 56 + h) * 56 + w) * 384;
            }
#pragma unroll
            for (int j = 0; j < 4; j++) {
                int col = n0 + wn + j * 16 + l16;
                float v = acc[i][j][r] + bias[col];
                if (EPI == EPI_QKV) {
                    int which = col / 384, head = (col >> 5) % 12, hd = col & 31;
                    u16* dst = (which == 0) ? o0 : ((which == 1) ? o1 : o2);
                    dst[(size_t)(widx * 12 + head) * 1568 + n * 32 + hd] = f2b(v);
                } else if (EPI == EPI_PROJ) {
                    dout[pbase + col] = v + xres[pbase + col];
                } else if (EPI == EPI_MLP1) {
                    float ge = 0.5f * v * (1.0f + erff(v * 0.70710678f));
                    o0[(size_t)row * 768 + col] = f2b(ge);
                } else {  // MLP2: dout += v
                    size_t o = (size_t)row * 384 + col;
                    dout[o] = v + dout[o];
                }
            }
        }
    }
}

// ---------------- Attention: one block per (window, head); in-place over q slice --------
__global__ __launch_bounds__(128)
void attn_kernel(u16* __restrict__ q, const u16* __restrict__ k,
                 const u16* __restrict__ v, const float* __restrict__ rpb,
                 const float* __restrict__ mask, const float* __restrict__ lsc,
                 u16* __restrict__ out) {
    int widx = blockIdx.x, head = blockIdx.y, tid = threadIdx.x;
    __shared__ float qs[49 * 32], ks[49 * 33], vs[49 * 32], lg[49 * 49];
    size_t base = (size_t)(widx * 12 + head) * 1568;
    for (int i = tid; i < 1568; i += 128) {
        qs[i] = b2f(q[base + i]);
        ks[(i >> 5) * 33 + (i & 31)] = b2f(k[base + i]);
        vs[i] = b2f(v[base + i]);
    }
    __syncthreads();
    if (tid < 49) {
        float s = 0.0f;
        for (int d = 0; d < 32; d++) { float x = qs[tid * 32 + d]; s += x * x; }
        float sc = 1.0f / fmaxf(sqrtf(s), 1e-12f);
        for (int d = 0; d < 32; d++) qs[tid * 32 + d] *= sc;
    } else if (tid >= 64 && tid < 113) {
        int r = tid - 64;
        float s = 0.0f;
        for (int d = 0; d < 32; d++) { float x = ks[r * 33 + d]; s += x * x; }
        float sc = 1.0f / fmaxf(sqrtf(s), 1e-12f);
        for (int d = 0; d < 32; d++) ks[r * 33 + d] *= sc;
    }
    __syncthreads();
    float scale = expf(fminf(lsc[head], 4.6051702f));
    const float* rp = rpb + (size_t)head * 2401;
    const float* mk = mask + (size_t)(widx & 63) * 2401;
    for (int idx = tid; idx < 2401; idx += 128) {
        int i = idx / 49, j = idx % 49;
        float d = 0.0f;
        for (int t = 0; t < 32; t++) d += qs[i * 32 + t] * ks[j * 33 + t];
        lg[idx] = d * scale + rp[idx] + mk[idx];
    }
    __syncthreads();
    if (tid < 49) {
        float m = -1e30f;
        for (int j = 0; j < 49; j++) m = fmaxf(m, lg[tid * 49 + j]);
        float s = 0.0f;
        for (int j = 0; j < 49; j++) { float e = expf(lg[tid * 49 + j] - m); lg[tid * 49 + j] = e; s += e; }
        float inv = 1.0f / s;
        for (int j = 0; j < 49; j++) lg[tid * 49 + j] *= inv;
    }
    __syncthreads();
    for (int idx = tid; idx < 1568; idx += 128) {
        int n = idx >> 5, d = idx & 31;
        float o = 0.0f;
        for (int j = 0; j < 49; j++) o += lg[n * 49 + j] * vs[j * 32 + d];
        out[base + n * 32 + d] = f2b(o);   // in-place over q slice (w,h)
    }
}

// ---------------- launch ----------------
extern "C" void kernel_launch(void* const* d_in, const int* in_sizes, int n_in,
                              void* d_out, int out_size, void* d_ws, size_t ws_size,
                              hipStream_t stream) {
    const float* x      = (const float*)d_in[0];
    const float* mask   = (const float*)d_in[1];
    const float* n1g    = (const float*)d_in[2];
    const float* n1b    = (const float*)d_in[3];
    const float* qkv_w  = (const float*)d_in[4];
    const float* qkv_b  = (const float*)d_in[5];
    const float* proj_w = (const float*)d_in[6];
    const float* proj_b = (const float*)d_in[7];
    const float* cpb_w1 = (const float*)d_in[8];
    const float* cpb_b1 = (const float*)d_in[9];
    const float* cpb_w2 = (const float*)d_in[10];
    const float* lscale = (const float*)d_in[11];
    const float* n2g    = (const float*)d_in[12];
    const float* n2b    = (const float*)d_in[13];
    const float* mlp_w1 = (const float*)d_in[14];
    const float* mlp_b1 = (const float*)d_in[15];
    const float* mlp_w2 = (const float*)d_in[16];
    const float* mlp_b2 = (const float*)d_in[17];

    char* ws = (char*)d_ws;
    const size_t SLOT = 77070336ULL;       // 100352*384*2 bytes (bf16 slot)
    float*  tab    = (float*)(ws);                 // 8112 B
    float*  rpb    = (float*)(ws + 16384);         // 115248 B
    float2* stats1 = (float2*)(ws + (1 << 20));    // 802816 B
    float2* stats2 = (float2*)(ws + (2 << 20));    // 802816 B
    u16* qb     = (u16*)(ws + (4 << 20));
    u16* kb     = (u16*)(ws + (4 << 20) + SLOT);
    u16* vb     = (u16*)d_out;              // bf16 v staged in d_out (dead before proj writes)
    u16* attn_o = qb;                       // attention writes in-place over q slices
    u16* hidden = qb;                       // q+k slots (154 MB) reused for MLP hidden
    float* dout = (float*)d_out;
    // peak ws usage: 4 MB + 2*SLOT ~= 158 MB

    cpb_tab_kernel<<<169, 512, 0, stream>>>(cpb_w1, cpb_b1, cpb_w2, tab);
    cpb_gather_kernel<<<113, 256, 0, stream>>>(tab, rpb);
    ln_stats_kernel<<<25088, 256, 0, stream>>>(x, stats1);
    gemm_mfma<SRC_WINLN, EPI_QKV><<<dim3(9, 784), 256, 0, stream>>>(
        x, qkv_w, qkv_b, 384, stats1, n1g, n1b, qb, kb, vb, nullptr, nullptr);
    attn_kernel<<<dim3(2048, 12), 128, 0, stream>>>(qb, kb, vb, rpb, mask, lscale, attn_o);
    gemm_mfma<SRC_HEADMAJ, EPI_PROJ><<<dim3(3, 784), 256, 0, stream>>>(
        attn_o, proj_w, proj_b, 384, nullptr, nullptr, nullptr,
        nullptr, nullptr, nullptr, x, dout);
    ln_stats_kernel<<<25088, 256, 0, stream>>>(dout, stats2);
    gemm_mfma<SRC_RASTLN, EPI_MLP1><<<dim3(6, 784), 256, 0, stream>>>(
        dout, mlp_w1, mlp_b1, 384, stats2, n2g, n2b,
        hidden, nullptr, nullptr, nullptr, nullptr);
    gemm_mfma<SRC_PLAIN, EPI_MLP2><<<dim3(3, 784), 256, 0, stream>>>(
        hidden, mlp_w2, mlp_b2, 768, nullptr, nullptr, nullptr,
        nullptr, nullptr, nullptr, nullptr, dout);
}